// Round 10
// baseline (274.114 us; speedup 1.0000x reference)
//
#include <hip/hip_runtime.h>
#include <hip/hip_bf16.h>

#define NN 100000
#define NE 600000
#define PAD 40   // max degree slots; P(Poisson(6) >= 40) ~ 1e-24

using bf16 = __hip_bfloat16;
typedef float f32x4 __attribute__((ext_vector_type(4)));
typedef short s16x8 __attribute__((ext_vector_type(8)));
typedef unsigned int u32x2 __attribute__((ext_vector_type(2)));
typedef unsigned int u32x4 __attribute__((ext_vector_type(4)));

__device__ __forceinline__ float bu2f(unsigned int u16) {
    union { float f; unsigned int i; } c; c.i = u16 << 16; return c.f;
}
__device__ __forceinline__ unsigned int f2bu(float f) {
    bf16 h = __float2bfloat16(f);
    return (unsigned int)*reinterpret_cast<unsigned short*>(&h);
}
__device__ __forceinline__ u32x2 st4bf(float4 a) {
    u32x2 u;
    u.x = f2bu(a.x) | (f2bu(a.y) << 16);
    u.y = f2bu(a.z) | (f2bu(a.w) << 16);
    return u;
}
__device__ __forceinline__ void up8(uint4 u, float* a) {
    a[0] = bu2f(u.x & 0xffffu); a[1] = bu2f(u.x >> 16);
    a[2] = bu2f(u.y & 0xffffu); a[3] = bu2f(u.y >> 16);
    a[4] = bu2f(u.z & 0xffffu); a[5] = bu2f(u.z >> 16);
    a[6] = bu2f(u.w & 0xffffu); a[7] = bu2f(u.w >> 16);
}
__device__ __forceinline__ void up4(uint2 u, float* a) {
    a[0] = bu2f(u.x & 0xffffu); a[1] = bu2f(u.x >> 16);
    a[2] = bu2f(u.y & 0xffffu); a[3] = bu2f(u.y >> 16);
}
// 4B edge record: src in bits [31:15], positive-bf16 weight in bits [14:0]
// record 0 decodes to src=0, w=+0.0 -> safe zero-pad filler
__device__ __forceinline__ int rec_src(unsigned int r) { return (int)(r >> 15); }
__device__ __forceinline__ float rec_w(unsigned int r) { return bu2f(r & 0x7fffu); }

// ---------- prep: zero cnt/x0x1 + bf16 weight transposes ----------
__global__ void k_prep(int* cnt, float* x0x1,
                       const float* W2, const float* W3, const float* W4,
                       short* Wt2, short* Wt3, short* Wt4) {
    int i = blockIdx.x * 256 + threadIdx.x;
    if (i < NN) cnt[i] = 0;
    if (i < 64) x0x1[i] = 0.0f;
    if (i < 4096) {                       // W2: [k=32][n=128] -> Wt2[n][k]
        int n = i >> 5, k = i & 31;
        Wt2[n * 32 + k] = (short)f2bu(W2[k * 128 + n]);
    }
    if (i >= 4096 && i < 20480) {         // W3: [128][128] -> Wt3[n][k]
        int j = i - 4096; int n = j >> 7, k = j & 127;
        Wt3[n * 128 + k] = (short)f2bu(W3[k * 128 + n]);
    }
    if (i >= 20480 && i < 24576) {        // W4: [k=128][n=32] -> Wt4[n][k]
        int j = i - 20480; int n = j >> 7, k = j & 127;
        Wt4[n * 128 + k] = (short)f2bu(W4[k * 32 + n]);
    }
}

// ---------- padded-CSR fill: 4B packed record ----------
__global__ void k_fill(const int* srcI, const int* dstI, const float* ew,
                       int* cnt, unsigned int* edges) {
    int e = blockIdx.x * 256 + threadIdx.x;
    if (e >= NE) return;
    int d = dstI[e];
    int r = atomicAdd(&cnt[d], 1);
    if (r < PAD)
        edges[(size_t)d * PAD + r] = ((unsigned int)srcI[e] << 15) | (f2bu(ew[e]) & 0x7fffu);
}

// deg = 1 + sum(ew) -> dinv; clamp cnt; zero-pad row to >=12 slots and to quad
// boundary; write xs = dinv*x
__global__ void k_deg(int* cnt, unsigned int* edges, float* dinv,
                      const float* x, float* xs) {
    int n = blockIdx.x * 256 + threadIdx.x;
    if (n >= NN) return;
    int len = cnt[n];
    if (len > PAD) { len = PAD; cnt[n] = PAD; }
    unsigned int* row = edges + (size_t)n * PAD;
    int lenr = (len + 3) & ~3;
    if (lenr < 12) lenr = 12;             // pad slots get record 0 (src=0, w=+0)
    for (int i = len; i < lenr; i++) row[i] = 0;
    float s = 1.0f;
    for (int i = 0; i < len; i++) s += rec_w(row[i]);
    float di = rsqrtf(s);
    dinv[n] = di;
    const float4* x4 = (const float4*)x;
    float4 a = x4[(size_t)n * 2], b = x4[(size_t)n * 2 + 1];
    a.x *= di; a.y *= di; a.z *= di; a.w *= di;
    b.x *= di; b.y *= di; b.z *= di; b.w *= di;
    ((float4*)xs)[(size_t)n * 2] = a;
    ((float4*)xs)[(size_t)n * 2 + 1] = b;
}

// ---------- L1 fused: aggregate @8 (2 thr/node) + VALU GEMM 8->32 + bias + relu
//            + colmax + store hs1 = dinv*h1 bf16 ----------
// 8-record prologue (32 VGPR payload, <=64 total -> 8 waves/SIMD); tail for deg>8.
__global__ __launch_bounds__(256) void k_l1(const float* __restrict__ xs,
        const float* __restrict__ dinv, const int* __restrict__ cnt,
        const unsigned int* __restrict__ edges, const float* __restrict__ Wf,
        const float* __restrict__ bias, unsigned int* __restrict__ hW,
        float* __restrict__ xmax) {
    __shared__ float xsl[128 * 12];
    __shared__ int smax[32];
    const int base = blockIdx.x * 128;
    const int t = threadIdx.x;
    const int nl = t >> 1, g = t & 1;
    int n = base + nl;
    const bool valid = (n < NN);
    if (!valid) n = NN - 1;               // duplicate last node (harmless for colmax)
    if (t < 32) smax[t] = 0;
    // P1: aggregate (4 of 8 channels per thread)
    const float4* h4 = (const float4*)xs;
    float4 acc = h4[(size_t)n * 2 + g];
    {
        int len = cnt[n];
        const uint4* row4 = (const uint4*)(edges + (size_t)n * PAD);
        uint4 r0 = row4[0], r1 = row4[1];
        unsigned int rec[8] = {r0.x, r0.y, r0.z, r0.w, r1.x, r1.y, r1.z, r1.w};
        float4 gg[8];
#pragma unroll
        for (int e = 0; e < 8; e++) gg[e] = h4[(size_t)rec_src(rec[e]) * 2 + g];
#pragma unroll
        for (int e = 0; e < 8; e++) {
            float w = rec_w(rec[e]);
            acc.x = fmaf(w, gg[e].x, acc.x); acc.y = fmaf(w, gg[e].y, acc.y);
            acc.z = fmaf(w, gg[e].z, acc.z); acc.w = fmaf(w, gg[e].w, acc.w);
        }
        int lenq = (len + 3) >> 2;
        for (int q = 2; q < lenq; q++) {
            uint4 rr = row4[q];
            float4 v0 = h4[(size_t)rec_src(rr.x) * 2 + g];
            float4 v1 = h4[(size_t)rec_src(rr.y) * 2 + g];
            float4 v2 = h4[(size_t)rec_src(rr.z) * 2 + g];
            float4 v3 = h4[(size_t)rec_src(rr.w) * 2 + g];
            float w0 = rec_w(rr.x), w1 = rec_w(rr.y), w2 = rec_w(rr.z), w3 = rec_w(rr.w);
            acc.x = fmaf(w0, v0.x, acc.x); acc.y = fmaf(w0, v0.y, acc.y);
            acc.z = fmaf(w0, v0.z, acc.z); acc.w = fmaf(w0, v0.w, acc.w);
            acc.x = fmaf(w1, v1.x, acc.x); acc.y = fmaf(w1, v1.y, acc.y);
            acc.z = fmaf(w1, v1.z, acc.z); acc.w = fmaf(w1, v1.w, acc.w);
            acc.x = fmaf(w2, v2.x, acc.x); acc.y = fmaf(w2, v2.y, acc.y);
            acc.z = fmaf(w2, v2.z, acc.z); acc.w = fmaf(w2, v2.w, acc.w);
            acc.x = fmaf(w3, v3.x, acc.x); acc.y = fmaf(w3, v3.y, acc.y);
            acc.z = fmaf(w3, v3.z, acc.z); acc.w = fmaf(w3, v3.w, acc.w);
        }
        float dn = dinv[n];
        acc.x *= dn; acc.y *= dn; acc.z *= dn; acc.w *= dn;
    }
    *(float4*)&xsl[nl * 12 + g * 4] = acc;
    __syncthreads();
    // P2: GEMM 8->32, thread g computes cols [16g, 16g+16)
    float4 o[4];
#pragma unroll
    for (int j = 0; j < 4; j++) o[j] = make_float4(0.f, 0.f, 0.f, 0.f);
    const float4* wr = (const float4*)Wf;     // W1 [8][32] row-major, 8 float4/row
#pragma unroll
    for (int k = 0; k < 8; k++) {
        float xv = xsl[nl * 12 + k];
#pragma unroll
        for (int j = 0; j < 4; j++) {
            float4 w = wr[k * 8 + g * 4 + j];
            o[j].x = fmaf(xv, w.x, o[j].x);
            o[j].y = fmaf(xv, w.y, o[j].y);
            o[j].z = fmaf(xv, w.z, o[j].z);
            o[j].w = fmaf(xv, w.w, o[j].w);
        }
    }
    float dn = dinv[n];
#pragma unroll
    for (int j = 0; j < 4; j++) {
        float4 bb = ((const float4*)bias)[g * 4 + j];
        o[j].x = fmaxf(o[j].x + bb.x, 0.f);
        o[j].y = fmaxf(o[j].y + bb.y, 0.f);
        o[j].z = fmaxf(o[j].z + bb.z, 0.f);
        o[j].w = fmaxf(o[j].w + bb.w, 0.f);
        atomicMax(&smax[g * 16 + j * 4 + 0], __float_as_int(o[j].x));
        atomicMax(&smax[g * 16 + j * 4 + 1], __float_as_int(o[j].y));
        atomicMax(&smax[g * 16 + j * 4 + 2], __float_as_int(o[j].z));
        atomicMax(&smax[g * 16 + j * 4 + 3], __float_as_int(o[j].w));
        if (valid) {
            float4 sc = make_float4(o[j].x * dn, o[j].y * dn, o[j].z * dn, o[j].w * dn);
            ((u32x2*)hW)[(size_t)n * 8 + g * 4 + j] = st4bf(sc);
        }
    }
    __syncthreads();
    if (t < 32) atomicMax((int*)&xmax[t], smax[t]);
}

// ---------- f2b v2: 128 thr / 16 nodes per block, fused agg(32) + W2-MFMA + W3-MFMA ----------
__global__ __launch_bounds__(128) void k_f2b(const unsigned int* __restrict__ hs1,
        const float* __restrict__ dinv, const int* __restrict__ cnt,
        const unsigned int* __restrict__ edges, const short* __restrict__ Wt2,
        const short* __restrict__ Wt3, const float* __restrict__ b2,
        unsigned short* __restrict__ T) {
    __shared__ short xs[16 * 40];
    __shared__ short hs[16 * 136];
    const int base = blockIdx.x * 16;
    const int t = threadIdx.x;
    // P1: aggregate h1 (32-wide), 8 threads/node, 8B/thread/edge
    {
        int nl = t >> 3, c = t & 7;
        int n = base + nl;
        float acc[4] = {0.f, 0.f, 0.f, 0.f};
        if (n < NN) {
            const uint2* h2v = (const uint2*)hs1;
            float a[4];
            up4(h2v[(size_t)n * 8 + c], a);
#pragma unroll
            for (int j = 0; j < 4; j++) acc[j] = a[j];
            int len = cnt[n];
            const uint4* row4 = (const uint4*)(edges + (size_t)n * PAD);
            uint4 r0 = row4[0], r1 = row4[1], r2 = row4[2];
            unsigned int rec[12] = {r0.x, r0.y, r0.z, r0.w, r1.x, r1.y, r1.z, r1.w,
                                    r2.x, r2.y, r2.z, r2.w};
            uint2 gg[12];
#pragma unroll
            for (int e = 0; e < 12; e++) gg[e] = h2v[(size_t)rec_src(rec[e]) * 8 + c];
#pragma unroll
            for (int e = 0; e < 12; e++) {
                float w = rec_w(rec[e]);
                float a0[4];
                up4(gg[e], a0);
#pragma unroll
                for (int j = 0; j < 4; j++) acc[j] = fmaf(w, a0[j], acc[j]);
            }
            int lenq = (len + 3) >> 2;
            for (int q = 3; q < lenq; q++) {
                uint4 rr = row4[q];
                uint2 u0 = h2v[(size_t)rec_src(rr.x) * 8 + c];
                uint2 u1 = h2v[(size_t)rec_src(rr.y) * 8 + c];
                uint2 u2 = h2v[(size_t)rec_src(rr.z) * 8 + c];
                uint2 u3 = h2v[(size_t)rec_src(rr.w) * 8 + c];
                float w0 = rec_w(rr.x), w1 = rec_w(rr.y);
                float w2 = rec_w(rr.z), w3 = rec_w(rr.w);
                float a0[4];
                up4(u0, a0);
#pragma unroll
                for (int j = 0; j < 4; j++) acc[j] = fmaf(w0, a0[j], acc[j]);
                up4(u1, a0);
#pragma unroll
                for (int j = 0; j < 4; j++) acc[j] = fmaf(w1, a0[j], acc[j]);
                up4(u2, a0);
#pragma unroll
                for (int j = 0; j < 4; j++) acc[j] = fmaf(w2, a0[j], acc[j]);
                up4(u3, a0);
#pragma unroll
                for (int j = 0; j < 4; j++) acc[j] = fmaf(w3, a0[j], acc[j]);
            }
            float dn = dinv[n];
#pragma unroll
            for (int j = 0; j < 4; j++) acc[j] *= dn;
        }
        u32x2 p;
        p.x = f2bu(acc[0]) | (f2bu(acc[1]) << 16);
        p.y = f2bu(acc[2]) | (f2bu(acc[3]) << 16);
        *(u32x2*)&xs[nl * 40 + c * 4] = p;
    }
    __syncthreads();
    const int wave = t >> 6;
    const int lane = t & 63;
    const int m = lane & 15, quad = lane >> 4;
    // P2: W2 MFMA 32->128 (+b2+relu) -> hs; wave w computes N-tiles [4w, 4w+4)
    {
        s16x8 a = *(const s16x8*)&xs[m * 40 + quad * 8];
        f32x4 acc[4];
#pragma unroll
        for (int i = 0; i < 4; i++) {
            int nt = wave * 4 + i;
            s16x8 b = *(const s16x8*)(Wt2 + (size_t)(nt * 16 + m) * 32 + quad * 8);
            acc[i] = (f32x4){0.f, 0.f, 0.f, 0.f};
            acc[i] = __builtin_amdgcn_mfma_f32_16x16x32_bf16(a, b, acc[i], 0, 0, 0);
        }
#pragma unroll
        for (int i = 0; i < 4; i++) {
            int nt = wave * 4 + i;
            float bb = b2[nt * 16 + m];
#pragma unroll
            for (int r = 0; r < 4; r++) {
                int row = quad * 4 + r;
                float v = fmaxf(acc[i][r] + bb, 0.f);
                hs[row * 136 + nt * 16 + m] = (short)f2bu(v);
            }
        }
    }
    __syncthreads();
    // P3: W3 MFMA 128->128 (*dinv); load full-row A first, barrier, then overwrite hs
    {
        s16x8 a2[4];
#pragma unroll
        for (int s = 0; s < 4; s++)
            a2[s] = *(const s16x8*)&hs[m * 136 + s * 32 + quad * 8];
        __syncthreads();   // all A-fragments read before any wave overwrites hs
        f32x4 acc[4];
#pragma unroll
        for (int i = 0; i < 4; i++) acc[i] = (f32x4){0.f, 0.f, 0.f, 0.f};
#pragma unroll
        for (int s = 0; s < 4; s++) {
#pragma unroll
            for (int i = 0; i < 4; i++) {
                int nt = wave * 4 + i;
                s16x8 b = *(const s16x8*)(Wt3 + ((size_t)(nt * 16 + m) * 128 + s * 32 + quad * 8));
                acc[i] = __builtin_amdgcn_mfma_f32_16x16x32_bf16(a2[s], b, acc[i], 0, 0, 0);
            }
        }
        float dsc[4];
#pragma unroll
        for (int r = 0; r < 4; r++) {
            int nd = base + quad * 4 + r;
            dsc[r] = (nd < NN) ? dinv[nd] : 1.0f;
        }
#pragma unroll
        for (int i = 0; i < 4; i++) {
            int nt = wave * 4 + i;
#pragma unroll
            for (int r = 0; r < 4; r++)
                hs[(quad * 4 + r) * 136 + nt * 16 + m] = (short)f2bu(acc[i][r] * dsc[r]);
        }
        // store own-wave columns [64*wave, 64*wave+64) of each node row
        __builtin_amdgcn_s_waitcnt(0);  // drain lgkm before reading own-wave LDS writes
        int nl = lane >> 2, ch = lane & 3;
        int node = base + nl;
        if (node < NN) {
            int cs = wave * 64 + ch * 16;
            *(uint4*)(T + (size_t)node * 128 + cs) = *(const uint4*)&hs[nl * 136 + cs];
            *(uint4*)(T + (size_t)node * 128 + cs + 8) = *(const uint4*)&hs[nl * 136 + cs + 8];
        }
    }
}

// ---------- agW4: fused L3 aggregate(128) + b3 + relu + MFMA 128->32 (*dinv) ----------
// 256 threads = 16 nodes/block (16 thr/node, 16B gathers). 8-record prologue.
__global__ __launch_bounds__(256) void k_agW4(const uint4* __restrict__ hin,
        const float* __restrict__ dinv, const int* __restrict__ cnt,
        const unsigned int* __restrict__ edges, const float* __restrict__ bias,
        const short* __restrict__ Wt4, unsigned short* __restrict__ Out) {
    __shared__ short ht[16 * 136];
    const int base = blockIdx.x * 16;
    const int t = threadIdx.x;
    int nl = t >> 4, c = t & 15;
    int n = base + nl;
    float acc[8];
    bool valid = (n < NN);
    if (valid) {
        float a[8];
        up8(hin[(size_t)n * 16 + c], a);
#pragma unroll
        for (int j = 0; j < 8; j++) acc[j] = a[j];
        int len = cnt[n];
        const uint4* row4 = (const uint4*)(edges + (size_t)n * PAD);
        uint4 r0 = row4[0], r1 = row4[1];
        unsigned int rec[8] = {r0.x, r0.y, r0.z, r0.w, r1.x, r1.y, r1.z, r1.w};
        uint4 gg[8];
#pragma unroll
        for (int e = 0; e < 8; e++) gg[e] = hin[(size_t)rec_src(rec[e]) * 16 + c];
#pragma unroll
        for (int e = 0; e < 8; e++) {
            float w = rec_w(rec[e]);
            float a0[8];
            up8(gg[e], a0);
#pragma unroll
            for (int j = 0; j < 8; j++) acc[j] = fmaf(w, a0[j], acc[j]);
        }
        int lenq = (len + 3) >> 2;
        for (int q = 2; q < lenq; q++) {
            uint4 rr = row4[q];
            uint4 u0 = hin[(size_t)rec_src(rr.x) * 16 + c];
            uint4 u1 = hin[(size_t)rec_src(rr.y) * 16 + c];
            uint4 u2 = hin[(size_t)rec_src(rr.z) * 16 + c];
            uint4 u3 = hin[(size_t)rec_src(rr.w) * 16 + c];
            float w0 = rec_w(rr.x), w1 = rec_w(rr.y);
            float w2 = rec_w(rr.z), w3 = rec_w(rr.w);
            float a0[8];
            up8(u0, a0);
#pragma unroll
            for (int j = 0; j < 8; j++) acc[j] = fmaf(w0, a0[j], acc[j]);
            up8(u1, a0);
#pragma unroll
            for (int j = 0; j < 8; j++) acc[j] = fmaf(w1, a0[j], acc[j]);
            up8(u2, a0);
#pragma unroll
            for (int j = 0; j < 8; j++) acc[j] = fmaf(w2, a0[j], acc[j]);
            up8(u3, a0);
#pragma unroll
            for (int j = 0; j < 8; j++) acc[j] = fmaf(w3, a0[j], acc[j]);
        }
        float dn = dinv[n];
#pragma unroll
        for (int j = 0; j < 8; j++)
            acc[j] = fmaxf(fmaf(dn, acc[j], bias[c * 8 + j]), 0.f);
    } else {
#pragma unroll
        for (int j = 0; j < 8; j++) acc[j] = 0.f;
    }
    {
        uint4 o;
        o.x = f2bu(acc[0]) | (f2bu(acc[1]) << 16);
        o.y = f2bu(acc[2]) | (f2bu(acc[3]) << 16);
        o.z = f2bu(acc[4]) | (f2bu(acc[5]) << 16);
        o.w = f2bu(acc[6]) | (f2bu(acc[7]) << 16);
        *(uint4*)&ht[nl * 136 + c * 8] = o;
    }
    __syncthreads();
    if (t < 64) {
        const int lane = t;
        const int m = lane & 15, quad = lane >> 4;
        s16x8 a[4];
#pragma unroll
        for (int s = 0; s < 4; s++)
            a[s] = *(const s16x8*)&ht[m * 136 + s * 32 + quad * 8];
        f32x4 acc2[2];
#pragma unroll
        for (int nt = 0; nt < 2; nt++) acc2[nt] = (f32x4){0.f, 0.f, 0.f, 0.f};
#pragma unroll
        for (int s = 0; s < 4; s++) {
#pragma unroll
            for (int nt = 0; nt < 2; nt++) {
                s16x8 b = *(const s16x8*)(Wt4 + ((size_t)(nt * 16 + m) * 128 + s * 32 + quad * 8));
                acc2[nt] = __builtin_amdgcn_mfma_f32_16x16x32_bf16(a[s], b, acc2[nt], 0, 0, 0);
            }
        }
        float dsc[4];
#pragma unroll
        for (int r = 0; r < 4; r++) {
            int nd = base + quad * 4 + r;
            dsc[r] = (nd < NN) ? dinv[nd] : 0.f;
        }
#pragma unroll
        for (int nt = 0; nt < 2; nt++) {
#pragma unroll
            for (int r = 0; r < 4; r++)
                ht[(quad * 4 + r) * 136 + nt * 16 + m] = (short)f2bu(acc2[nt][r] * dsc[r]);
        }
        __builtin_amdgcn_s_waitcnt(0);  // drain lgkm before reading own-wave LDS writes
        int nl2 = lane >> 2, ch = lane & 3;
        int node = base + nl2;
        if (node < NN)
            *(uint4*)(Out + (size_t)node * 32 + ch * 8) = *(const uint4*)&ht[nl2 * 136 + ch * 8];
    }
}

// ---------- bf16 aggregate (pre-scaled input), 16B/lane, 8-record prologue ----------
// EPI: 1 = *dinv + bias + relu + store bf16;  3 = *dinv + bias + relu + colmax, NO store
template<int W, int EPI>
__global__ __launch_bounds__(256) void k_ag16(const uint4* __restrict__ hin,
        const float* __restrict__ dinv, const int* __restrict__ cnt,
        const unsigned int* __restrict__ edges, const float* __restrict__ bias,
        uint4* __restrict__ outB, float* __restrict__ xmax) {
    constexpr int TPN = W / 8;
    __shared__ int smax[(EPI == 3) ? W : 1];
    int tid = blockIdx.x * 256 + threadIdx.x;
    int n = tid / TPN, c = tid % TPN;
    if (EPI == 3) {
        if (threadIdx.x < W) smax[threadIdx.x] = 0;
        __syncthreads();
    }
    float acc[8];
    bool valid = (n < NN);
    if (valid) {
        float a[8];
        up8(hin[(size_t)n * TPN + c], a);
#pragma unroll
        for (int j = 0; j < 8; j++) acc[j] = a[j];
        int len = cnt[n];
        const uint4* row4 = (const uint4*)(edges + (size_t)n * PAD);
        uint4 r0 = row4[0], r1 = row4[1];
        unsigned int rec[8] = {r0.x, r0.y, r0.z, r0.w, r1.x, r1.y, r1.z, r1.w};
        uint4 gg[8];
#pragma unroll
        for (int e = 0; e < 8; e++) gg[e] = hin[(size_t)rec_src(rec[e]) * TPN + c];
#pragma unroll
        for (int e = 0; e < 8; e++) {
            float w = rec_w(rec[e]);
            float a0[8];
            up8(gg[e], a0);
#pragma unroll
            for (int j = 0; j < 8; j++) acc[j] = fmaf(w, a0[j], acc[j]);
        }
        int lenq = (len + 3) >> 2;
        for (int q = 2; q < lenq; q++) {
            uint4 rr = row4[q];
            uint4 u0 = hin[(size_t)rec_src(rr.x) * TPN + c];
            uint4 u1 = hin[(size_t)rec_src(rr.y) * TPN + c];
            uint4 u2 = hin[(size_t)rec_src(rr.z) * TPN + c];
            uint4 u3 = hin[(size_t)rec_src(rr.w) * TPN + c];
            float w0 = rec_w(rr.x), w1 = rec_w(rr.y);
            float w2 = rec_w(rr.z), w3 = rec_w(rr.w);
            float a0[8];
            up8(u0, a0);
#pragma unroll
            for (int j = 0; j < 8; j++) acc[j] = fmaf(w0, a0[j], acc[j]);
            up8(u1, a0);
#pragma unroll
            for (int j = 0; j < 8; j++) acc[j] = fmaf(w1, a0[j], acc[j]);
            up8(u2, a0);
#pragma unroll
            for (int j = 0; j < 8; j++) acc[j] = fmaf(w2, a0[j], acc[j]);
            up8(u3, a0);
#pragma unroll
            for (int j = 0; j < 8; j++) acc[j] = fmaf(w3, a0[j], acc[j]);
        }
        float dn = dinv[n];
#pragma unroll
        for (int j = 0; j < 8; j++)
            acc[j] = fmaxf(fmaf(dn, acc[j], bias[c * 8 + j]), 0.f);
        if (EPI == 1) {
            uint4 o;
            o.x = f2bu(acc[0]) | (f2bu(acc[1]) << 16);
            o.y = f2bu(acc[2]) | (f2bu(acc[3]) << 16);
            o.z = f2bu(acc[4]) | (f2bu(acc[5]) << 16);
            o.w = f2bu(acc[6]) | (f2bu(acc[7]) << 16);
            outB[(size_t)n * TPN + c] = o;
        } else {
#pragma unroll
            for (int j = 0; j < 8; j++) atomicMax(&smax[c * 8 + j], __float_as_int(acc[j]));
        }
    }
    if (EPI == 3) {
        __syncthreads();
        if (threadIdx.x < W) atomicMax((int*)&xmax[threadIdx.x], smax[threadIdx.x]);
    }
}

// ---------- head MLP + softmax + fp32 output ----------
__global__ void k_mlp(const float* x0x1, const float* C2,
                      const float* L1W, const float* L1b,
                      const float* L2W, const float* L2b,
                      const float* L3W, const float* L3b, float* out) {
    __shared__ float code[68], z1[128], z2[128];
    int t = threadIdx.x;
    if (t < 64) code[t] = x0x1[t];
    else if (t < 68) code[t] = C2[t - 64];
    __syncthreads();
    float acc = L1b[t];
    for (int i = 0; i < 68; i++) acc = fmaf(code[i], L1W[i * 128 + t], acc);
    z1[t] = fmaxf(acc, 0.f);
    __syncthreads();
    acc = L2b[t];
    for (int i = 0; i < 128; i++) acc = fmaf(z1[i], L2W[i * 128 + t], acc);
    z2[t] = fmaxf(acc, 0.f);
    __syncthreads();
    if (t == 0) {
        float lg[10];
        for (int c = 0; c < 10; c++) {
            float a = L3b[c];
            for (int i = 0; i < 128; i++) a = fmaf(z2[i], L3W[i * 10 + c], a);
            lg[c] = a;
        }
        float m = lg[0];
        for (int c = 1; c < 10; c++) m = fmaxf(m, lg[c]);
        float s = 0.f;
        for (int c = 0; c < 10; c++) { lg[c] = __expf(lg[c] - m); s += lg[c]; }
        float inv = 1.f / s;
        for (int c = 0; c < 10; c++) out[c] = lg[c] * inv;
    }
    if (t < 68) out[10 + t] = code[t];
}

extern "C" void kernel_launch(void* const* d_in, const int* in_sizes, int n_in,
                              void* d_out, int out_size, void* d_ws, size_t ws_size,
                              hipStream_t stream) {
    const float* x   = (const float*)d_in[0];
    const int*   ei  = (const int*)d_in[1];
    const float* ew  = (const float*)d_in[2];
    const float* C2  = (const float*)d_in[4];
    const float* W1  = (const float*)d_in[5],  * b1 = (const float*)d_in[6];
    const float* W2  = (const float*)d_in[7],  * b2 = (const float*)d_in[8];
    const float* W3  = (const float*)d_in[9],  * b3 = (const float*)d_in[10];
    const float* W4  = (const float*)d_in[11], * b4 = (const float*)d_in[12];
    const float* L1W = (const float*)d_in[13], * L1b = (const float*)d_in[14];
    const float* L2W = (const float*)d_in[15], * L2b = (const float*)d_in[16];
    const float* L3W = (const float*)d_in[17], * L3b = (const float*)d_in[18];
    float* out = (float*)d_out;
    (void)in_sizes; (void)n_in; (void)out_size; (void)ws_size;

    const size_t szF = (size_t)NN * 128 * 4;
    char* p = (char*)d_ws;
    char* H       = p;          p += szF;
    char* T       = p;          p += szF;
    unsigned int* edges = (unsigned int*)p; p += (size_t)NN * PAD * 4;  // 16MB packed
    float* dinv   = (float*)p;  p += (size_t)NN * 4;
    int*   cnt    = (int*)p;    p += (size_t)NN * 4;
    float* xs     = (float*)p;  p += (size_t)NN * 8 * 4;     // pre-scaled x
    float* x0x1   = (float*)p;  p += 256 * 4;
    short* Wt2    = (short*)p;  p += 4096 * 2;
    short* Wt3    = (short*)p;  p += 16384 * 2;
    short* Wt4    = (short*)p;  p += 4096 * 2;

    const int* srcI = ei;
    const int* dstI = ei + NE;

    dim3 B(256);
    k_prep<<<dim3((NN + 255) / 256), B, 0, stream>>>(cnt, x0x1, W2, W3, W4, Wt2, Wt3, Wt4);
    k_fill<<<dim3((NE + 255) / 256), B, 0, stream>>>(srcI, dstI, ew, cnt, edges);
    k_deg<<<dim3((NN + 255) / 256), B, 0, stream>>>(cnt, edges, dinv, x, xs);

    // L1 fused: agg xs @8 + gemm 8->32 +bias+relu+max -> H = hs1 bf16 (dinv-scaled)
    k_l1<<<dim3((NN + 127) / 128), B, 0, stream>>>(
        xs, dinv, cnt, edges, W1, b1, (unsigned int*)H, x0x1);
    // L2+L3-GEMM fused: agg hs1 @32 + MFMA 32->128 (+b2+relu) + MFMA 128->128 (*dinv) -> T
    k_f2b<<<dim3((NN + 15) / 16), dim3(128), 0, stream>>>(
        (const unsigned int*)H, dinv, cnt, edges, Wt2, Wt3, b2, (unsigned short*)T);
    // L3-agg + L4-GEMM fused: agg T @128 *dinv +b3+relu + MFMA 128->32 (*dinv) -> H (32-wide)
    k_agW4<<<dim3((NN + 15) / 16), B, 0, stream>>>(
        (const uint4*)T, dinv, cnt, edges, b3, Wt4, (unsigned short*)H);
    // L4 aggregate: agg H @32 *dinv +b4+relu+max (no store)
    k_ag16<32, 3><<<dim3((NN * 4 + 255) / 256), B, 0, stream>>>(
        (const uint4*)H, dinv, cnt, edges, b4, nullptr, x0x1 + 32);

    k_mlp<<<dim3(1), dim3(128), 0, stream>>>(x0x1, C2, L1W, L1b, L2W, L2b, L3W, L3b, out);
}

// Round 11
// 267.733 us; speedup vs baseline: 1.0238x; 1.0238x over previous
//
#include <hip/hip_runtime.h>
#include <hip/hip_bf16.h>

#define NN 100000
#define NE 600000
#define PAD 40   // max degree slots; P(Poisson(6) >= 40) ~ 1e-24

using bf16 = __hip_bfloat16;
typedef float f32x4 __attribute__((ext_vector_type(4)));
typedef short s16x8 __attribute__((ext_vector_type(8)));
typedef unsigned int u32x2 __attribute__((ext_vector_type(2)));
typedef unsigned int u32x4 __attribute__((ext_vector_type(4)));

__device__ __forceinline__ float bu2f(unsigned int u16) {
    union { float f; unsigned int i; } c; c.i = u16 << 16; return c.f;
}
__device__ __forceinline__ unsigned int f2bu(float f) {
    bf16 h = __float2bfloat16(f);
    return (unsigned int)*reinterpret_cast<unsigned short*>(&h);
}
__device__ __forceinline__ u32x2 st4bf(float4 a) {
    u32x2 u;
    u.x = f2bu(a.x) | (f2bu(a.y) << 16);
    u.y = f2bu(a.z) | (f2bu(a.w) << 16);
    return u;
}
__device__ __forceinline__ void up8(uint4 u, float* a) {
    a[0] = bu2f(u.x & 0xffffu); a[1] = bu2f(u.x >> 16);
    a[2] = bu2f(u.y & 0xffffu); a[3] = bu2f(u.y >> 16);
    a[4] = bu2f(u.z & 0xffffu); a[5] = bu2f(u.z >> 16);
    a[6] = bu2f(u.w & 0xffffu); a[7] = bu2f(u.w >> 16);
}
__device__ __forceinline__ void up4(uint2 u, float* a) {
    a[0] = bu2f(u.x & 0xffffu); a[1] = bu2f(u.x >> 16);
    a[2] = bu2f(u.y & 0xffffu); a[3] = bu2f(u.y >> 16);
}
// 4B edge record: src in bits [31:15], positive-bf16 weight in bits [14:0]
// record 0 decodes to src=0, w=+0.0 -> safe zero-pad filler
__device__ __forceinline__ int rec_src(unsigned int r) { return (int)(r >> 15); }
__device__ __forceinline__ float rec_w(unsigned int r) { return bu2f(r & 0x7fffu); }

// ---------- prep: zero cnt/x0x1 + bf16 weight transposes ----------
__global__ void k_prep(int* cnt, float* x0x1,
                       const float* W2, const float* W3, const float* W4,
                       short* Wt2, short* Wt3, short* Wt4) {
    int i = blockIdx.x * 256 + threadIdx.x;
    if (i < NN) cnt[i] = 0;
    if (i < 64) x0x1[i] = 0.0f;
    if (i < 4096) {                       // W2: [k=32][n=128] -> Wt2[n][k]
        int n = i >> 5, k = i & 31;
        Wt2[n * 32 + k] = (short)f2bu(W2[k * 128 + n]);
    }
    if (i >= 4096 && i < 20480) {         // W3: [128][128] -> Wt3[n][k]
        int j = i - 4096; int n = j >> 7, k = j & 127;
        Wt3[n * 128 + k] = (short)f2bu(W3[k * 128 + n]);
    }
    if (i >= 20480 && i < 24576) {        // W4: [k=128][n=32] -> Wt4[n][k]
        int j = i - 20480; int n = j >> 7, k = j & 127;
        Wt4[n * 128 + k] = (short)f2bu(W4[k * 32 + n]);
    }
}

// ---------- padded-CSR fill: 4B packed record ----------
__global__ void k_fill(const int* srcI, const int* dstI, const float* ew,
                       int* cnt, unsigned int* edges) {
    int e = blockIdx.x * 256 + threadIdx.x;
    if (e >= NE) return;
    int d = dstI[e];
    int r = atomicAdd(&cnt[d], 1);
    if (r < PAD)
        edges[(size_t)d * PAD + r] = ((unsigned int)srcI[e] << 15) | (f2bu(ew[e]) & 0x7fffu);
}

// deg = 1 + sum(ew) -> dinv; clamp cnt; zero-pad row to >=12 slots (3 quads, branch-free
// gather prologue) and to quad boundary; write xs = dinv*x
__global__ void k_deg(int* cnt, unsigned int* edges, float* dinv,
                      const float* x, float* xs) {
    int n = blockIdx.x * 256 + threadIdx.x;
    if (n >= NN) return;
    int len = cnt[n];
    if (len > PAD) { len = PAD; cnt[n] = PAD; }
    unsigned int* row = edges + (size_t)n * PAD;
    int lenr = (len + 3) & ~3;
    if (lenr < 12) lenr = 12;             // pad slots get record 0 (src=0, w=+0)
    for (int i = len; i < lenr; i++) row[i] = 0;
    float s = 1.0f;
    for (int i = 0; i < len; i++) s += rec_w(row[i]);
    float di = rsqrtf(s);
    dinv[n] = di;
    const float4* x4 = (const float4*)x;
    float4 a = x4[(size_t)n * 2], b = x4[(size_t)n * 2 + 1];
    a.x *= di; a.y *= di; a.z *= di; a.w *= di;
    b.x *= di; b.y *= di; b.z *= di; b.w *= di;
    ((float4*)xs)[(size_t)n * 2] = a;
    ((float4*)xs)[(size_t)n * 2 + 1] = b;
}

// ---------- L1 aggregate: fp32, 2 lanes/node, pre-scaled input xs ----------
// branch-free 3-quad prologue (12 gathers in flight), rare tail loop for deg>12
__global__ __launch_bounds__(256) void k_ag8(const float* __restrict__ xs,
        const float* __restrict__ dinv, const int* __restrict__ cnt,
        const unsigned int* __restrict__ edges, float* __restrict__ outF) {
    int tid = blockIdx.x * 256 + threadIdx.x;
    int n = tid >> 1, g = tid & 1;
    if (n >= NN) return;
    const float4* h4 = (const float4*)xs;
    float4 acc = h4[(size_t)n * 2 + g];
    int len = cnt[n];
    const uint4* row4 = (const uint4*)(edges + (size_t)n * PAD);
    uint4 r0 = row4[0], r1 = row4[1], r2 = row4[2];
    unsigned int rec[12] = {r0.x, r0.y, r0.z, r0.w, r1.x, r1.y, r1.z, r1.w,
                            r2.x, r2.y, r2.z, r2.w};
    float4 gg[12];
#pragma unroll
    for (int e = 0; e < 12; e++) gg[e] = h4[(size_t)rec_src(rec[e]) * 2 + g];
#pragma unroll
    for (int e = 0; e < 12; e++) {
        float w = rec_w(rec[e]);
        acc.x = fmaf(w, gg[e].x, acc.x); acc.y = fmaf(w, gg[e].y, acc.y);
        acc.z = fmaf(w, gg[e].z, acc.z); acc.w = fmaf(w, gg[e].w, acc.w);
    }
    int lenq = (len + 3) >> 2;
    for (int q = 3; q < lenq; q++) {
        uint4 rr = row4[q];
        float4 v0 = h4[(size_t)rec_src(rr.x) * 2 + g];
        float4 v1 = h4[(size_t)rec_src(rr.y) * 2 + g];
        float4 v2 = h4[(size_t)rec_src(rr.z) * 2 + g];
        float4 v3 = h4[(size_t)rec_src(rr.w) * 2 + g];
        float w0 = rec_w(rr.x), w1 = rec_w(rr.y), w2 = rec_w(rr.z), w3 = rec_w(rr.w);
        acc.x = fmaf(w0, v0.x, acc.x); acc.y = fmaf(w0, v0.y, acc.y);
        acc.z = fmaf(w0, v0.z, acc.z); acc.w = fmaf(w0, v0.w, acc.w);
        acc.x = fmaf(w1, v1.x, acc.x); acc.y = fmaf(w1, v1.y, acc.y);
        acc.z = fmaf(w1, v1.z, acc.z); acc.w = fmaf(w1, v1.w, acc.w);
        acc.x = fmaf(w2, v2.x, acc.x); acc.y = fmaf(w2, v2.y, acc.y);
        acc.z = fmaf(w2, v2.z, acc.z); acc.w = fmaf(w2, v2.w, acc.w);
        acc.x = fmaf(w3, v3.x, acc.x); acc.y = fmaf(w3, v3.y, acc.y);
        acc.z = fmaf(w3, v3.z, acc.z); acc.w = fmaf(w3, v3.w, acc.w);
    }
    float dn = dinv[n];
    acc.x *= dn; acc.y *= dn; acc.z *= dn; acc.w *= dn;
    ((float4*)outF)[(size_t)n * 2 + g] = acc;
}

// ---------- VALU GEMM (8->32): +bias+relu+colmax; store hs1 = dinv*h1 bf16 ----------
__global__ __launch_bounds__(256) void k_gemm8(const float* __restrict__ hin,
                                               const float* __restrict__ Wf,
                                               const float* __restrict__ dinv,
                                               unsigned int* __restrict__ hW,
                                               const float* __restrict__ bias,
                                               float* xmax) {
    __shared__ float xs[256 * 12];
    __shared__ int smax[32];
    const int base = blockIdx.x * 256;
    const int t = threadIdx.x;
#pragma unroll
    for (int i = 0; i < 2; i++) {
        int idx = t + 256 * i;
        int row = idx >> 1, k4 = idx & 1;
        int node = base + row;
        if (node >= NN) node = NN - 1;
        float4 v = ((const float4*)hin)[(size_t)node * 2 + k4];
        *(float4*)&xs[row * 12 + 4 * k4] = v;
    }
    if (t < 32) smax[t] = 0;
    __syncthreads();
    const int cg = t & 7, ng = t >> 3;
    float4 acc[8];
#pragma unroll
    for (int i = 0; i < 8; i++) acc[i] = make_float4(0.f, 0.f, 0.f, 0.f);
    const float4* wr = (const float4*)Wf;
#pragma unroll
    for (int k = 0; k < 8; k++) {
        float4 w = wr[k * 8 + cg];
#pragma unroll
        for (int i = 0; i < 8; i++) {
            float xv = xs[(ng * 8 + i) * 12 + k];
            acc[i].x = fmaf(xv, w.x, acc[i].x);
            acc[i].y = fmaf(xv, w.y, acc[i].y);
            acc[i].z = fmaf(xv, w.z, acc[i].z);
            acc[i].w = fmaf(xv, w.w, acc[i].w);
        }
    }
    float4 bb = ((const float4*)bias)[cg];
    float4 mx = make_float4(0.f, 0.f, 0.f, 0.f);
#pragma unroll
    for (int i = 0; i < 8; i++) {
        int node = base + ng * 8 + i;
        acc[i].x = fmaxf(acc[i].x + bb.x, 0.f);
        acc[i].y = fmaxf(acc[i].y + bb.y, 0.f);
        acc[i].z = fmaxf(acc[i].z + bb.z, 0.f);
        acc[i].w = fmaxf(acc[i].w + bb.w, 0.f);
        mx.x = fmaxf(mx.x, acc[i].x); mx.y = fmaxf(mx.y, acc[i].y);
        mx.z = fmaxf(mx.z, acc[i].z); mx.w = fmaxf(mx.w, acc[i].w);
        if (node < NN) {
            float dn = dinv[node];
            float4 sc = make_float4(acc[i].x * dn, acc[i].y * dn, acc[i].z * dn, acc[i].w * dn);
            ((u32x2*)hW)[(size_t)node * 8 + cg] = st4bf(sc);
        }
    }
    atomicMax(&smax[cg * 4 + 0], __float_as_int(mx.x));
    atomicMax(&smax[cg * 4 + 1], __float_as_int(mx.y));
    atomicMax(&smax[cg * 4 + 2], __float_as_int(mx.z));
    atomicMax(&smax[cg * 4 + 3], __float_as_int(mx.w));
    __syncthreads();
    if (t < 32) atomicMax((int*)&xmax[t], smax[t]);
}

// ---------- f2b v2: 128 thr / 16 nodes per block, fused agg(32) + W2-MFMA + W3-MFMA ----------
// P1: 8 thr/node, uint2 (8B) gathers. P2/P3: 2 waves split the 8 N-tiles.
__global__ __launch_bounds__(128) void k_f2b(const unsigned int* __restrict__ hs1,
        const float* __restrict__ dinv, const int* __restrict__ cnt,
        const unsigned int* __restrict__ edges, const short* __restrict__ Wt2,
        const short* __restrict__ Wt3, const float* __restrict__ b2,
        unsigned short* __restrict__ T) {
    __shared__ short xs[16 * 40];
    __shared__ short hs[16 * 136];
    const int base = blockIdx.x * 16;
    const int t = threadIdx.x;
    // P1: aggregate h1 (32-wide), 8 threads/node, 8B/thread/edge
    {
        int nl = t >> 3, c = t & 7;
        int n = base + nl;
        float acc[4] = {0.f, 0.f, 0.f, 0.f};
        if (n < NN) {
            const uint2* h2v = (const uint2*)hs1;
            float a[4];
            up4(h2v[(size_t)n * 8 + c], a);
#pragma unroll
            for (int j = 0; j < 4; j++) acc[j] = a[j];
            int len = cnt[n];
            const uint4* row4 = (const uint4*)(edges + (size_t)n * PAD);
            uint4 r0 = row4[0], r1 = row4[1], r2 = row4[2];
            unsigned int rec[12] = {r0.x, r0.y, r0.z, r0.w, r1.x, r1.y, r1.z, r1.w,
                                    r2.x, r2.y, r2.z, r2.w};
            uint2 gg[12];
#pragma unroll
            for (int e = 0; e < 12; e++) gg[e] = h2v[(size_t)rec_src(rec[e]) * 8 + c];
#pragma unroll
            for (int e = 0; e < 12; e++) {
                float w = rec_w(rec[e]);
                float a0[4];
                up4(gg[e], a0);
#pragma unroll
                for (int j = 0; j < 4; j++) acc[j] = fmaf(w, a0[j], acc[j]);
            }
            int lenq = (len + 3) >> 2;
            for (int q = 3; q < lenq; q++) {
                uint4 rr = row4[q];
                uint2 u0 = h2v[(size_t)rec_src(rr.x) * 8 + c];
                uint2 u1 = h2v[(size_t)rec_src(rr.y) * 8 + c];
                uint2 u2 = h2v[(size_t)rec_src(rr.z) * 8 + c];
                uint2 u3 = h2v[(size_t)rec_src(rr.w) * 8 + c];
                float w0 = rec_w(rr.x), w1 = rec_w(rr.y);
                float w2 = rec_w(rr.z), w3 = rec_w(rr.w);
                float a0[4];
                up4(u0, a0);
#pragma unroll
                for (int j = 0; j < 4; j++) acc[j] = fmaf(w0, a0[j], acc[j]);
                up4(u1, a0);
#pragma unroll
                for (int j = 0; j < 4; j++) acc[j] = fmaf(w1, a0[j], acc[j]);
                up4(u2, a0);
#pragma unroll
                for (int j = 0; j < 4; j++) acc[j] = fmaf(w2, a0[j], acc[j]);
                up4(u3, a0);
#pragma unroll
                for (int j = 0; j < 4; j++) acc[j] = fmaf(w3, a0[j], acc[j]);
            }
            float dn = dinv[n];
#pragma unroll
            for (int j = 0; j < 4; j++) acc[j] *= dn;
        }
        u32x2 p;
        p.x = f2bu(acc[0]) | (f2bu(acc[1]) << 16);
        p.y = f2bu(acc[2]) | (f2bu(acc[3]) << 16);
        *(u32x2*)&xs[nl * 40 + c * 4] = p;
    }
    __syncthreads();
    const int wave = t >> 6;
    const int lane = t & 63;
    const int m = lane & 15, quad = lane >> 4;
    // P2: W2 MFMA 32->128 (+b2+relu) -> hs; wave w computes N-tiles [4w, 4w+4)
    {
        s16x8 a = *(const s16x8*)&xs[m * 40 + quad * 8];
        f32x4 acc[4];
#pragma unroll
        for (int i = 0; i < 4; i++) {
            int nt = wave * 4 + i;
            s16x8 b = *(const s16x8*)(Wt2 + (size_t)(nt * 16 + m) * 32 + quad * 8);
            acc[i] = (f32x4){0.f, 0.f, 0.f, 0.f};
            acc[i] = __builtin_amdgcn_mfma_f32_16x16x32_bf16(a, b, acc[i], 0, 0, 0);
        }
#pragma unroll
        for (int i = 0; i < 4; i++) {
            int nt = wave * 4 + i;
            float bb = b2[nt * 16 + m];
#pragma unroll
            for (int r = 0; r < 4; r++) {
                int row = quad * 4 + r;
                float v = fmaxf(acc[i][r] + bb, 0.f);
                hs[row * 136 + nt * 16 + m] = (short)f2bu(v);
            }
        }
    }
    __syncthreads();
    // P3: W3 MFMA 128->128 (*dinv); load full-row A first, barrier, then overwrite hs
    {
        s16x8 a2[4];
#pragma unroll
        for (int s = 0; s < 4; s++)
            a2[s] = *(const s16x8*)&hs[m * 136 + s * 32 + quad * 8];
        __syncthreads();   // all A-fragments read before any wave overwrites hs
        f32x4 acc[4];
#pragma unroll
        for (int i = 0; i < 4; i++) acc[i] = (f32x4){0.f, 0.f, 0.f, 0.f};
#pragma unroll
        for (int s = 0; s < 4; s++) {
#pragma unroll
            for (int i = 0; i < 4; i++) {
                int nt = wave * 4 + i;
                s16x8 b = *(const s16x8*)(Wt3 + ((size_t)(nt * 16 + m) * 128 + s * 32 + quad * 8));
                acc[i] = __builtin_amdgcn_mfma_f32_16x16x32_bf16(a2[s], b, acc[i], 0, 0, 0);
            }
        }
        float dsc[4];
#pragma unroll
        for (int r = 0; r < 4; r++) {
            int nd = base + quad * 4 + r;
            dsc[r] = (nd < NN) ? dinv[nd] : 1.0f;
        }
#pragma unroll
        for (int i = 0; i < 4; i++) {
            int nt = wave * 4 + i;
#pragma unroll
            for (int r = 0; r < 4; r++)
                hs[(quad * 4 + r) * 136 + nt * 16 + m] = (short)f2bu(acc[i][r] * dsc[r]);
        }
        // store own-wave columns [64*wave, 64*wave+64) of each node row
        __builtin_amdgcn_s_waitcnt(0);  // drain lgkm before reading own-wave LDS writes
        int nl = lane >> 2, ch = lane & 3;
        int node = base + nl;
        if (node < NN) {
            int cs = wave * 64 + ch * 16;
            *(uint4*)(T + (size_t)node * 128 + cs) = *(const uint4*)&hs[nl * 136 + cs];
            *(uint4*)(T + (size_t)node * 128 + cs + 8) = *(const uint4*)&hs[nl * 136 + cs + 8];
        }
    }
}

// ---------- agW4: fused L3 aggregate(128) + b3 + relu + MFMA 128->32 (*dinv) ----------
// 256 threads = 16 nodes/block (16 thr/node, 16B gathers, 12-record prologue).
__global__ __launch_bounds__(256) void k_agW4(const uint4* __restrict__ hin,
        const float* __restrict__ dinv, const int* __restrict__ cnt,
        const unsigned int* __restrict__ edges, const float* __restrict__ bias,
        const short* __restrict__ Wt4, unsigned short* __restrict__ Out) {
    __shared__ short ht[16 * 136];
    const int base = blockIdx.x * 16;
    const int t = threadIdx.x;
    int nl = t >> 4, c = t & 15;
    int n = base + nl;
    float acc[8];
    bool valid = (n < NN);
    if (valid) {
        float a[8];
        up8(hin[(size_t)n * 16 + c], a);
#pragma unroll
        for (int j = 0; j < 8; j++) acc[j] = a[j];
        int len = cnt[n];
        const uint4* row4 = (const uint4*)(edges + (size_t)n * PAD);
        uint4 r0 = row4[0], r1 = row4[1], r2 = row4[2];
        unsigned int rec[12] = {r0.x, r0.y, r0.z, r0.w, r1.x, r1.y, r1.z, r1.w,
                                r2.x, r2.y, r2.z, r2.w};
        uint4 gg[12];
#pragma unroll
        for (int e = 0; e < 12; e++) gg[e] = hin[(size_t)rec_src(rec[e]) * 16 + c];
#pragma unroll
        for (int e = 0; e < 12; e++) {
            float w = rec_w(rec[e]);
            float a0[8];
            up8(gg[e], a0);
#pragma unroll
            for (int j = 0; j < 8; j++) acc[j] = fmaf(w, a0[j], acc[j]);
        }
        int lenq = (len + 3) >> 2;
        for (int q = 3; q < lenq; q++) {
            uint4 rr = row4[q];
            uint4 u0 = hin[(size_t)rec_src(rr.x) * 16 + c];
            uint4 u1 = hin[(size_t)rec_src(rr.y) * 16 + c];
            uint4 u2 = hin[(size_t)rec_src(rr.z) * 16 + c];
            uint4 u3 = hin[(size_t)rec_src(rr.w) * 16 + c];
            float w0 = rec_w(rr.x), w1 = rec_w(rr.y);
            float w2 = rec_w(rr.z), w3 = rec_w(rr.w);
            float a0[8];
            up8(u0, a0);
#pragma unroll
            for (int j = 0; j < 8; j++) acc[j] = fmaf(w0, a0[j], acc[j]);
            up8(u1, a0);
#pragma unroll
            for (int j = 0; j < 8; j++) acc[j] = fmaf(w1, a0[j], acc[j]);
            up8(u2, a0);
#pragma unroll
            for (int j = 0; j < 8; j++) acc[j] = fmaf(w2, a0[j], acc[j]);
            up8(u3, a0);
#pragma unroll
            for (int j = 0; j < 8; j++) acc[j] = fmaf(w3, a0[j], acc[j]);
        }
        float dn = dinv[n];
#pragma unroll
        for (int j = 0; j < 8; j++)
            acc[j] = fmaxf(fmaf(dn, acc[j], bias[c * 8 + j]), 0.f);
    } else {
#pragma unroll
        for (int j = 0; j < 8; j++) acc[j] = 0.f;
    }
    {
        uint4 o;
        o.x = f2bu(acc[0]) | (f2bu(acc[1]) << 16);
        o.y = f2bu(acc[2]) | (f2bu(acc[3]) << 16);
        o.z = f2bu(acc[4]) | (f2bu(acc[5]) << 16);
        o.w = f2bu(acc[6]) | (f2bu(acc[7]) << 16);
        *(uint4*)&ht[nl * 136 + c * 8] = o;
    }
    __syncthreads();
    if (t < 64) {
        const int lane = t;
        const int m = lane & 15, quad = lane >> 4;
        s16x8 a[4];
#pragma unroll
        for (int s = 0; s < 4; s++)
            a[s] = *(const s16x8*)&ht[m * 136 + s * 32 + quad * 8];
        f32x4 acc2[2];
#pragma unroll
        for (int nt = 0; nt < 2; nt++) acc2[nt] = (f32x4){0.f, 0.f, 0.f, 0.f};
#pragma unroll
        for (int s = 0; s < 4; s++) {
#pragma unroll
            for (int nt = 0; nt < 2; nt++) {
                s16x8 b = *(const s16x8*)(Wt4 + ((size_t)(nt * 16 + m) * 128 + s * 32 + quad * 8));
                acc2[nt] = __builtin_amdgcn_mfma_f32_16x16x32_bf16(a[s], b, acc2[nt], 0, 0, 0);
            }
        }
        float dsc[4];
#pragma unroll
        for (int r = 0; r < 4; r++) {
            int nd = base + quad * 4 + r;
            dsc[r] = (nd < NN) ? dinv[nd] : 0.f;
        }
#pragma unroll
        for (int nt = 0; nt < 2; nt++) {
#pragma unroll
            for (int r = 0; r < 4; r++)
                ht[(quad * 4 + r) * 136 + nt * 16 + m] = (short)f2bu(acc2[nt][r] * dsc[r]);
        }
        __builtin_amdgcn_s_waitcnt(0);  // drain lgkm before reading own-wave LDS writes
        int nl2 = lane >> 2, ch = lane & 3;
        int node = base + nl2;
        if (node < NN)
            *(uint4*)(Out + (size_t)node * 32 + ch * 8) = *(const uint4*)&ht[nl2 * 136 + ch * 8];
    }
}

// ---------- bf16 aggregate (pre-scaled input), 16B/lane, 12-record prologue ----------
// EPI: 1 = *dinv + bias + relu + store bf16;  3 = *dinv + bias + relu + colmax, NO store
template<int W, int EPI>
__global__ __launch_bounds__(256) void k_ag16(const uint4* __restrict__ hin,
        const float* __restrict__ dinv, const int* __restrict__ cnt,
        const unsigned int* __restrict__ edges, const float* __restrict__ bias,
        uint4* __restrict__ outB, float* __restrict__ xmax) {
    constexpr int TPN = W / 8;
    __shared__ int smax[(EPI == 3) ? W : 1];
    int tid = blockIdx.x * 256 + threadIdx.x;
    int n = tid / TPN, c = tid % TPN;
    if (EPI == 3) {
        if (threadIdx.x < W) smax[threadIdx.x] = 0;
        __syncthreads();
    }
    float acc[8];
    bool valid = (n < NN);
    if (valid) {
        float a[8];
        up8(hin[(size_t)n * TPN + c], a);
#pragma unroll
        for (int j = 0; j < 8; j++) acc[j] = a[j];
        int len = cnt[n];
        const uint4* row4 = (const uint4*)(edges + (size_t)n * PAD);
        uint4 r0 = row4[0], r1 = row4[1], r2 = row4[2];
        unsigned int rec[12] = {r0.x, r0.y, r0.z, r0.w, r1.x, r1.y, r1.z, r1.w,
                                r2.x, r2.y, r2.z, r2.w};
        uint4 gg[12];
#pragma unroll
        for (int e = 0; e < 12; e++) gg[e] = hin[(size_t)rec_src(rec[e]) * TPN + c];
#pragma unroll
        for (int e = 0; e < 12; e++) {
            float w = rec_w(rec[e]);
            float a0[8];
            up8(gg[e], a0);
#pragma unroll
            for (int j = 0; j < 8; j++) acc[j] = fmaf(w, a0[j], acc[j]);
        }
        int lenq = (len + 3) >> 2;
        for (int q = 3; q < lenq; q++) {
            uint4 rr = row4[q];
            uint4 u0 = hin[(size_t)rec_src(rr.x) * TPN + c];
            uint4 u1 = hin[(size_t)rec_src(rr.y) * TPN + c];
            uint4 u2 = hin[(size_t)rec_src(rr.z) * TPN + c];
            uint4 u3 = hin[(size_t)rec_src(rr.w) * TPN + c];
            float w0 = rec_w(rr.x), w1 = rec_w(rr.y);
            float w2 = rec_w(rr.z), w3 = rec_w(rr.w);
            float a0[8];
            up8(u0, a0);
#pragma unroll
            for (int j = 0; j < 8; j++) acc[j] = fmaf(w0, a0[j], acc[j]);
            up8(u1, a0);
#pragma unroll
            for (int j = 0; j < 8; j++) acc[j] = fmaf(w1, a0[j], acc[j]);
            up8(u2, a0);
#pragma unroll
            for (int j = 0; j < 8; j++) acc[j] = fmaf(w2, a0[j], acc[j]);
            up8(u3, a0);
#pragma unroll
            for (int j = 0; j < 8; j++) acc[j] = fmaf(w3, a0[j], acc[j]);
        }
        float dn = dinv[n];
#pragma unroll
        for (int j = 0; j < 8; j++)
            acc[j] = fmaxf(fmaf(dn, acc[j], bias[c * 8 + j]), 0.f);
        if (EPI == 1) {
            uint4 o;
            o.x = f2bu(acc[0]) | (f2bu(acc[1]) << 16);
            o.y = f2bu(acc[2]) | (f2bu(acc[3]) << 16);
            o.z = f2bu(acc[4]) | (f2bu(acc[5]) << 16);
            o.w = f2bu(acc[6]) | (f2bu(acc[7]) << 16);
            outB[(size_t)n * TPN + c] = o;
        } else {
#pragma unroll
            for (int j = 0; j < 8; j++) atomicMax(&smax[c * 8 + j], __float_as_int(acc[j]));
        }
    }
    if (EPI == 3) {
        __syncthreads();
        if (threadIdx.x < W) atomicMax((int*)&xmax[threadIdx.x], smax[threadIdx.x]);
    }
}

// ---------- head MLP + softmax + fp32 output ----------
__global__ void k_mlp(const float* x0x1, const float* C2,
                      const float* L1W, const float* L1b,
                      const float* L2W, const float* L2b,
                      const float* L3W, const float* L3b, float* out) {
    __shared__ float code[68], z1[128], z2[128];
    int t = threadIdx.x;
    if (t < 64) code[t] = x0x1[t];
    else if (t < 68) code[t] = C2[t - 64];
    __syncthreads();
    float acc = L1b[t];
    for (int i = 0; i < 68; i++) acc = fmaf(code[i], L1W[i * 128 + t], acc);
    z1[t] = fmaxf(acc, 0.f);
    __syncthreads();
    acc = L2b[t];
    for (int i = 0; i < 128; i++) acc = fmaf(z1[i], L2W[i * 128 + t], acc);
    z2[t] = fmaxf(acc, 0.f);
    __syncthreads();
    if (t == 0) {
        float lg[10];
        for (int c = 0; c < 10; c++) {
            float a = L3b[c];
            for (int i = 0; i < 128; i++) a = fmaf(z2[i], L3W[i * 10 + c], a);
            lg[c] = a;
        }
        float m = lg[0];
        for (int c = 1; c < 10; c++) m = fmaxf(m, lg[c]);
        float s = 0.f;
        for (int c = 0; c < 10; c++) { lg[c] = __expf(lg[c] - m); s += lg[c]; }
        float inv = 1.f / s;
        for (int c = 0; c < 10; c++) out[c] = lg[c] * inv;
    }
    if (t < 68) out[10 + t] = code[t];
}

extern "C" void kernel_launch(void* const* d_in, const int* in_sizes, int n_in,
                              void* d_out, int out_size, void* d_ws, size_t ws_size,
                              hipStream_t stream) {
    const float* x   = (const float*)d_in[0];
    const int*   ei  = (const int*)d_in[1];
    const float* ew  = (const float*)d_in[2];
    const float* C2  = (const float*)d_in[4];
    const float* W1  = (const float*)d_in[5],  * b1 = (const float*)d_in[6];
    const float* W2  = (const float*)d_in[7],  * b2 = (const float*)d_in[8];
    const float* W3  = (const float*)d_in[9],  * b3 = (const float*)d_in[10];
    const float* W4  = (const float*)d_in[11], * b4 = (const float*)d_in[12];
    const float* L1W = (const float*)d_in[13], * L1b = (const float*)d_in[14];
    const float* L2W = (const float*)d_in[15], * L2b = (const float*)d_in[16];
    const float* L3W = (const float*)d_in[17], * L3b = (const float*)d_in[18];
    float* out = (float*)d_out;
    (void)in_sizes; (void)n_in; (void)out_size; (void)ws_size;

    const size_t szF = (size_t)NN * 128 * 4;
    char* p = (char*)d_ws;
    char* H       = p;          p += szF;
    char* T       = p;          p += szF;
    unsigned int* edges = (unsigned int*)p; p += (size_t)NN * PAD * 4;  // 16MB packed
    float* dinv   = (float*)p;  p += (size_t)NN * 4;
    int*   cnt    = (int*)p;    p += (size_t)NN * 4;
    float* xs     = (float*)p;  p += (size_t)NN * 8 * 4;     // pre-scaled x
    float* x0x1   = (float*)p;  p += 256 * 4;
    short* Wt2    = (short*)p;  p += 4096 * 2;
    short* Wt3    = (short*)p;  p += 16384 * 2;
    short* Wt4    = (short*)p;  p += 4096 * 2;

    const int* srcI = ei;
    const int* dstI = ei + NE;

    dim3 B(256);
    k_prep<<<dim3((NN + 255) / 256), B, 0, stream>>>(cnt, x0x1, W2, W3, W4, Wt2, Wt3, Wt4);
    k_fill<<<dim3((NE + 255) / 256), B, 0, stream>>>(srcI, dstI, ew, cnt, edges);
    k_deg<<<dim3((NN + 255) / 256), B, 0, stream>>>(cnt, edges, dinv, x, xs);

    // L1: agg xs @8 -> T fp32; gemm 8->32 +bias+relu+max -> H = hs1 bf16 (dinv-scaled)
    k_ag8<<<dim3((NN * 2 + 255) / 256), B, 0, stream>>>(xs, dinv, cnt, edges, (float*)T);
    k_gemm8<<<dim3((NN + 255) / 256), B, 0, stream>>>((const float*)T, W1, dinv, (unsigned int*)H, b1, x0x1);
    // L2+L3-GEMM fused: agg hs1 @32 + MFMA 32->128 (+b2+relu) + MFMA 128->128 (*dinv) -> T
    k_f2b<<<dim3((NN + 15) / 16), dim3(128), 0, stream>>>(
        (const unsigned int*)H, dinv, cnt, edges, Wt2, Wt3, b2, (unsigned short*)T);
    // L3-agg + L4-GEMM fused: agg T @128 *dinv +b3+relu + MFMA 128->32 (*dinv) -> H (32-wide)
    k_agW4<<<dim3((NN + 15) / 16), B, 0, stream>>>(
        (const uint4*)T, dinv, cnt, edges, b3, Wt4, (unsigned short*)H);
    // L4 aggregate: agg H @32 *dinv +b4+relu+max (no store)
    k_ag16<32, 3><<<dim3((NN * 4 + 255) / 256), B, 0, stream>>>(
        (const uint4*)H, dinv, cnt, edges, b4, nullptr, x0x1 + 32);

    k_mlp<<<dim3(1), dim3(128), 0, stream>>>(x0x1, C2, L1W, L1b, L2W, L2b, L3W, L3b, out);
}